// Round 1
// baseline (627.969 us; speedup 1.0000x reference)
//
#include <hip/hip_runtime.h>

#define D 64

// Phase 1: per-edge scatter: agg[dst[e]] += w[e] * h[src[e]]
// One wave (64 lanes) per edge; lane = feature index.
__global__ __launch_bounds__(256) void edge_scatter_kernel(
    const float* __restrict__ h, const float* __restrict__ w,
    const int* __restrict__ src, const int* __restrict__ dst,
    float* __restrict__ agg, int E)
{
    int e = blockIdx.x * 4 + (threadIdx.x >> 6);
    int lane = threadIdx.x & 63;
    if (e >= E) return;
    int s = src[e];
    int d = dst[e];
    float wv = w[e];
    float val = wv * h[(size_t)s * D + lane];
    atomicAdd(&agg[(size_t)d * D + lane], val);
}

// Phase 2: out[n][j] = b[j] + sum_k h[n][k]*W[j][k] + sum_k agg[n][k]*W[j][64+k]
// W staged in LDS transposed: Wt[k*64+j] = W[j*128+k]  (conflict-free reads:
// consecutive lanes j -> consecutive LDS addresses).
// h[n]/agg[n] rows live in registers, broadcast across the wave via __shfl.
__global__ __launch_bounds__(256) void out_linear_kernel(
    const float* __restrict__ h, const float* __restrict__ agg,
    const float* __restrict__ W, const float* __restrict__ b,
    float* __restrict__ out, int N)
{
    __shared__ float Wt[128 * 64];  // 32 KB
    int lane = threadIdx.x & 63;
    int waveInBlock = threadIdx.x >> 6;
    int wavesPerBlock = blockDim.x >> 6;

    // Cooperative transpose-load of W into LDS.
    // idx -> j = idx & 63, k = idx >> 6 : consecutive threads write
    // consecutive LDS addresses (conflict-free); global read is strided
    // but W is 32 KB and L2-resident after the first touch.
    for (int idx = threadIdx.x; idx < 128 * 64; idx += blockDim.x) {
        int j = idx & 63;
        int k = idx >> 6;
        Wt[k * 64 + j] = W[j * 128 + k];
    }
    __syncthreads();

    float bj = b[lane];
    int wavesPerGrid = gridDim.x * wavesPerBlock;

    for (int n = blockIdx.x * wavesPerBlock + waveInBlock; n < N; n += wavesPerGrid) {
        float hreg = h[(size_t)n * D + lane];
        float areg = agg[(size_t)n * D + lane];
        float acc = bj;
        #pragma unroll
        for (int k = 0; k < 64; ++k) {
            float hk = __shfl(hreg, k, 64);
            float ak = __shfl(areg, k, 64);
            acc += hk * Wt[k * 64 + lane];
            acc += ak * Wt[(k + 64) * 64 + lane];
        }
        out[(size_t)n * D + lane] = acc;
    }
}

extern "C" void kernel_launch(void* const* d_in, const int* in_sizes, int n_in,
                              void* d_out, int out_size, void* d_ws, size_t ws_size,
                              hipStream_t stream) {
    const float* h   = (const float*)d_in[0];
    const float* w   = (const float*)d_in[1];
    const int*   src = (const int*)d_in[2];
    const int*   dst = (const int*)d_in[3];
    const float* W   = (const float*)d_in[4];
    const float* b   = (const float*)d_in[5];
    float* out = (float*)d_out;

    int N = in_sizes[0] / D;
    int E = in_sizes[1];

    size_t aggBytes = (size_t)N * D * sizeof(float);
    // Prefer workspace for agg; in-place on d_out is also safe (each wave
    // loads its full agg row into registers before writing out), used as
    // fallback if ws is too small.
    float* agg = (ws_size >= aggBytes) ? (float*)d_ws : out;

    hipMemsetAsync(agg, 0, aggBytes, stream);

    int edgeBlocks = (E + 3) / 4;  // 4 edges (waves) per 256-thread block
    edge_scatter_kernel<<<edgeBlocks, 256, 0, stream>>>(h, w, src, dst, agg, E);

    out_linear_kernel<<<2048, 256, 0, stream>>>(h, agg, W, b, out, N);
}